// Round 1
// baseline (12805.251 us; speedup 1.0000x reference)
//
#include <hip/hip_runtime.h>
#include <hip/hip_bf16.h>

using u16 = unsigned short;
typedef float  f32x4  __attribute__((ext_vector_type(4)));
typedef __bf16 bf16x8 __attribute__((ext_vector_type(8)));
typedef u16    u16x8  __attribute__((ext_vector_type(8)));

#define SEQ   2048
#define NTOK  4096
#define BM 128
#define BN 128
#define BK 32
#define LDSS 40   // LDS row stride in u16 (80 B) — padded to break bank aliasing

static __device__ __forceinline__ u16 f2bf(float f) {
    __hip_bfloat16 h = __float2bfloat16(f);   // RNE, compiler packs to v_cvt_pk_bf16_f32
    return __builtin_bit_cast(u16, h);
}
static __device__ __forceinline__ float gelu_exact(float x) {
    return 0.5f * x * (1.0f + erff(x * 0.70710678118654752440f));
}

// ---------------- strategy + token compaction ----------------
__global__ __launch_bounds__(256) void strat_kernel(
        const float* __restrict__ attn, int* __restrict__ cnts,
        int* __restrict__ idx2, int* __restrict__ idx1, int* __restrict__ idx0)
{
    const int b   = blockIdx.x;     // one block per batch
    const int tid = threadIdx.x;
    __shared__ float tok[SEQ];
    __shared__ float red[256];
    float lmax = -1e30f;
    for (int s = tid; s < SEQ; s += 256) {
        const float* p = attn + ((size_t)b * SEQ + s) * 16;
        float a[8];
        #pragma unroll
        for (int i = 0; i < 8; ++i) a[i] = p[i] + p[i + 8];   // numpy pairwise-style sum
        float v = ((a[0] + a[1]) + (a[2] + a[3])) + ((a[4] + a[5]) + (a[6] + a[7]));
        tok[s] = v;
        lmax = fmaxf(lmax, v);
    }
    red[tid] = lmax;
    __syncthreads();
    for (int s = 128; s > 0; s >>= 1) {
        if (tid < s) red[tid] = fmaxf(red[tid], red[tid + s]);
        __syncthreads();
    }
    const float m = red[0] + 1e-8f;
    for (int s = tid; s < SEQ; s += 256) {
        const float na = tok[s] / m;            // true division, matches ref rounding
        const int t = b * SEQ + s;
        if (na >= 0.7f)      { int p = atomicAdd(&cnts[0], 1); idx2[p] = t; }
        else if (na >= 0.3f) { int p = atomicAdd(&cnts[1], 1); idx1[p] = t; }
        else                 { int p = atomicAdd(&cnts[2], 1); idx0[p] = t; }
    }
}

// ---------------- tiled bf16 MFMA GEMM ----------------
// C[m,n] = A[m,:K] @ B[:K,n] (B fp32 row-major [K][N], transposed+converted in LDS)
// AMODE: 0 = A fp32 (convert inline), 1 = A bf16 (u16 rows, compact)
// AGATHER: A row m comes from idx[m] (over fp32 source)
// USE_CNT: effective M read from *cntp (device), rows >= count masked
// EPI: 0 = bf16 store to outb (opt. exact gelu), 1 = 1+sigmoid -> outf, 2 = outf *= value
// SCATTER: epilogue row = idx[m]
template<int AMODE, bool AGATHER, bool USE_CNT, int EPI, bool HAS_BIAS, bool ACT_GELU, bool SCATTER>
__global__ __launch_bounds__(256) void gemm_kernel(
    const float* __restrict__ Af, const u16* __restrict__ Abf,
    const float* __restrict__ Bsrc, const float* __restrict__ bias,
    const int* __restrict__ idx, const int* __restrict__ cntp,
    int M, int N, int K,
    u16* __restrict__ outb, float* __restrict__ outf)
{
    __shared__ u16 As[BM * LDSS];
    __shared__ u16 Bs[BN * LDSS];

    const int tid = threadIdx.x;
    const int bm = blockIdx.x, bn = blockIdx.y;   // bm fast => co-resident blocks share B panel
    int mcnt;
    if constexpr (USE_CNT) mcnt = *cntp; else mcnt = M;
    if (bm * BM >= mcnt) return;

    const int lane = tid & 63;
    const int wave = tid >> 6;
    const int wr = wave >> 1, wc = wave & 1;

    // A staging role: thread -> (row, 16-float half)
    const int ar  = tid >> 1;
    const int ah  = tid & 1;
    const int ari = bm * BM + ar;
    const bool arv = ari < mcnt;
    size_t arow_off;
    if constexpr (AGATHER) {
        int rg = arv ? idx[ari] : 0;
        arow_off = (size_t)rg * K;
    } else {
        arow_off = (size_t)ari * K;
    }

    // B staging role: thread -> (n, n+64) x 8 k's ; full-lane b128 LDS writes
    const int bnl = tid & 63;
    const int bkb = (tid >> 6) * 8;
    const int bn0 = bn * BN + bnl;
    const int bn1 = bn0 + 64;
    const bool bc0 = bn0 < N, bc1 = bn1 < N;

    f32x4 acc[4][4];
    #pragma unroll
    for (int i = 0; i < 4; ++i)
        #pragma unroll
        for (int j = 0; j < 4; ++j)
            acc[i][j] = (f32x4)(0.0f);

    for (int k0 = 0; k0 < K; k0 += BK) {
        // ---- stage A tile [BM][BK] ----
        {
            const int kc = k0 + ah * 16;
            const bool kval = (kc + 16 <= K);     // all K are multiples of 16
            u16x8 u0, u1;
            if constexpr (AMODE == 0) {
                float va[16];
                if (arv && kval) {
                    const f32x4* p = (const f32x4*)(Af + arow_off + kc);
                    f32x4 g0 = p[0], g1 = p[1], g2 = p[2], g3 = p[3];
                    #pragma unroll
                    for (int i = 0; i < 4; ++i) { va[i] = g0[i]; va[4+i] = g1[i]; va[8+i] = g2[i]; va[12+i] = g3[i]; }
                } else {
                    #pragma unroll
                    for (int i = 0; i < 16; ++i) va[i] = 0.f;
                }
                #pragma unroll
                for (int i = 0; i < 8; ++i) { u0[i] = f2bf(va[i]); u1[i] = f2bf(va[8 + i]); }
            } else {
                if (arv && kval) {
                    const u16x8* p = (const u16x8*)(Abf + arow_off + kc);
                    u0 = p[0]; u1 = p[1];
                } else {
                    #pragma unroll
                    for (int i = 0; i < 8; ++i) { u0[i] = 0; u1[i] = 0; }
                }
            }
            *(u16x8*)&As[ar * LDSS + ah * 16]     = u0;
            *(u16x8*)&As[ar * LDSS + ah * 16 + 8] = u1;
        }
        // ---- stage B tile: Bs[n][k] = bf16(B[k0+k][bn*128+n]) ----
        {
            float v0[8], v1[8];
            #pragma unroll
            for (int kk = 0; kk < 8; ++kk) {
                const int kg = k0 + bkb + kk;
                const bool kval = kg < K;
                const size_t ro = (size_t)kg * N;
                v0[kk] = (kval && bc0) ? Bsrc[ro + bn0] : 0.f;
                v1[kk] = (kval && bc1) ? Bsrc[ro + bn1] : 0.f;
            }
            u16x8 w0, w1;
            #pragma unroll
            for (int kk = 0; kk < 8; ++kk) { w0[kk] = f2bf(v0[kk]); w1[kk] = f2bf(v1[kk]); }
            *(u16x8*)&Bs[bnl * LDSS + bkb]        = w0;
            *(u16x8*)&Bs[(bnl + 64) * LDSS + bkb] = w1;
        }
        __syncthreads();
        // ---- MFMA: 16 per wave per K-step ----
        {
            const int kq = (lane >> 4) * 8;
            const int rA = wr * 64 + (lane & 15);
            const int rB = wc * 64 + (lane & 15);
            bf16x8 aF[4], bF[4];
            #pragma unroll
            for (int i = 0; i < 4; ++i)
                aF[i] = __builtin_bit_cast(bf16x8, *(const u16x8*)&As[(rA + i * 16) * LDSS + kq]);
            #pragma unroll
            for (int j = 0; j < 4; ++j)
                bF[j] = __builtin_bit_cast(bf16x8, *(const u16x8*)&Bs[(rB + j * 16) * LDSS + kq]);
            #pragma unroll
            for (int i = 0; i < 4; ++i)
                #pragma unroll
                for (int j = 0; j < 4; ++j)
                    acc[i][j] = __builtin_amdgcn_mfma_f32_16x16x32_bf16(aF[i], bF[j], acc[i][j], 0, 0, 0);
        }
        __syncthreads();
    }

    // ---- epilogue: C/D layout col = lane&15, row = (lane>>4)*4 + reg ----
    const int lrb = wr * 64 + ((lane >> 4) << 2);
    const int lcb = bn * BN + wc * 64 + (lane & 15);
    #pragma unroll
    for (int i = 0; i < 4; ++i) {
        #pragma unroll
        for (int q = 0; q < 4; ++q) {
            const int ri = bm * BM + lrb + i * 16 + q;
            if (USE_CNT && ri >= mcnt) continue;
            size_t orow;
            if constexpr (SCATTER) orow = (size_t)idx[ri] * N;
            else                   orow = (size_t)ri * N;
            #pragma unroll
            for (int j = 0; j < 4; ++j) {
                const int col = lcb + j * 16;
                if (col >= N) continue;
                float v = acc[i][j][q];
                if constexpr (HAS_BIAS) v += bias[col];
                if constexpr (EPI == 0) {
                    if constexpr (ACT_GELU) v = gelu_exact(v);
                    outb[orow + col] = f2bf(v);
                } else if constexpr (EPI == 1) {
                    outf[orow + col] = 1.f + 1.f / (1.f + __expf(-v));
                } else {
                    outf[orow + col] *= v;
                }
            }
        }
    }
}

extern "C" void kernel_launch(void* const* d_in, const int* in_sizes, int n_in,
                              void* d_out, int out_size, void* d_ws, size_t ws_size,
                              hipStream_t stream)
{
    (void)in_sizes; (void)n_in; (void)out_size; (void)ws_size;
    const float* h      = (const float*)d_in[0];
    const float* attn   = (const float*)d_in[1];
    const float* W_full = (const float*)d_in[2];
    const float* W_s1   = (const float*)d_in[3];
    const float* b_s1   = (const float*)d_in[4];
    const float* W_s2   = (const float*)d_in[5];
    const float* b_s2   = (const float*)d_in[6];
    const float* W_m1   = (const float*)d_in[7];
    const float* b_m1   = (const float*)d_in[8];
    const float* W_me   = (const float*)d_in[9];
    const float* b_me   = (const float*)d_in[10];
    const float* W_f1   = (const float*)d_in[11];
    const float* b_f1   = (const float*)d_in[12];
    const float* W_f2   = (const float*)d_in[13];
    const float* b_f2   = (const float*)d_in[14];
    float* out = (float*)d_out;

    char* ws = (char*)d_ws;
    int* cnts = (int*)ws;                               // [0]=n_full, [1]=n_sparse, [2]=n_minimal
    int* idx2 = (int*)(ws + 256);
    int* idx1 = (int*)(ws + 256 + NTOK * 4);
    int* idx0 = (int*)(ws + 256 + 2 * NTOK * 4);
    size_t off = (256 + (size_t)3 * NTOK * 4 + 255) & ~(size_t)255;
    u16* S1 = (u16*)(ws + off); off += (size_t)NTOK * 4000 * 2;   // gelu(h@W_s1+b), compact rows
    u16* M1 = (u16*)(ws + off); off += (size_t)NTOK * 2000 * 2;   // h@W_m1+b, compact rows
    u16* F1 = (u16*)(ws + off); off += (size_t)NTOK * 1600 * 2;   // gelu(h@W_f1+b), all tokens

    hipMemsetAsync(cnts, 0, 256, stream);
    strat_kernel<<<2, 256, 0, stream>>>(attn, cnts, idx2, idx1, idx0);

    // stage-1 projections (A = h fp32; S1/M1 gathered via index lists; outputs bf16)
    gemm_kernel<0, true,  true,  0, true,  true,  false><<<dim3(32, 32), 256, 0, stream>>>(
        h, nullptr, W_s1, b_s1, idx1, cnts + 1, NTOK, 4000, 1024, S1, nullptr);
    gemm_kernel<0, true,  true,  0, true,  false, false><<<dim3(32, 16), 256, 0, stream>>>(
        h, nullptr, W_m1, b_m1, idx0, cnts + 2, NTOK, 2000, 1024, M1, nullptr);
    gemm_kernel<0, false, false, 0, true,  true,  false><<<dim3(32, 13), 256, 0, stream>>>(
        h, nullptr, W_f1, b_f1, nullptr, nullptr, NTOK, 1600, 1024, F1, nullptr);

    // focus: out[t,v] = 1 + sigmoid(F1 @ W_f2 + b_f2)   (dense, covers every output element)
    gemm_kernel<1, false, false, 1, true,  false, false><<<dim3(32, 125), 256, 0, stream>>>(
        nullptr, F1, W_f2, b_f2, nullptr, nullptr, NTOK, 16000, 1600, nullptr, out);

    // tier logits, multiplied into out (each token in exactly one list)
    gemm_kernel<0, true,  true,  2, false, false, true><<<dim3(32, 125), 256, 0, stream>>>(
        h, nullptr, W_full, nullptr, idx2, cnts + 0, NTOK, 16000, 1024, nullptr, out);
    gemm_kernel<1, false, true,  2, true,  false, true><<<dim3(32, 125), 256, 0, stream>>>(
        nullptr, S1, W_s2, b_s2, idx1, cnts + 1, NTOK, 16000, 4000, nullptr, out);
    gemm_kernel<1, false, true,  2, true,  false, true><<<dim3(32, 125), 256, 0, stream>>>(
        nullptr, M1, W_me, b_me, idx0, cnts + 2, NTOK, 16000, 2000, nullptr, out);
}